// Round 2
// baseline (485.130 us; speedup 1.0000x reference)
//
#include <hip/hip_runtime.h>
#include <hip/hip_bf16.h>
#include <math.h>

#define BE   256
#define DIM  256
#define OUTD 128
#define LCL  256
#define LEV  512
#define NEGV -1e18f

typedef short  bf16x8  __attribute__((ext_vector_type(8)));
typedef float  floatx4 __attribute__((ext_vector_type(4)));

union BF1 { __hip_bfloat16 h; unsigned short u; };
union BF2 { __hip_bfloat162 h; unsigned int u; };

__device__ __forceinline__ float fast_tanh(float x) {
    float xc = fminf(fmaxf(x, -15.f), 15.f);
    float e = __expf(2.f * xc);                       // e^{2x}
    return (e - 1.f) * __builtin_amdgcn_rcpf(e + 1.f);
}

// ---------------------------------------------------------------------------
// K1: per-pair means (float4 streaming) + bias GEMVs + WT transpose fold.
// blocks [0,256): pair b -> means of claim (256 rows) and evidence (512 rows),
//   then bias_e = c_mean @ W1[D:], bias_c = e_mean @ W2[D:].
// blocks 256,257: convert+transpose W[:D] -> bf16 W^T (side = bid-256).
// ---------------------------------------------------------------------------
__global__ __launch_bounds__(512) void k_meanbias(
    const float* __restrict__ claim, const float* __restrict__ evidence,
    const float* __restrict__ W1, const float* __restrict__ W2,
    float* __restrict__ bias_e, float* __restrict__ bias_c,
    unsigned short* __restrict__ WT1, unsigned short* __restrict__ WT2)
{
    const int bid = blockIdx.x;
    const int t = threadIdx.x;
    if (bid >= BE) {
        const int side = bid - BE;
        const float* W = side ? W2 : W1;
        unsigned short* WT = side ? WT2 : WT1;
        for (int i = t; i < OUTD * DIM; i += 512) {
            const int d = i & (DIM - 1);
            const int n = i >> 8;
            BF1 c; c.h = __float2bfloat16(W[(size_t)d * OUTD + n]);
            WT[n * DIM + d] = c.u;           // contiguous writes per t-run
        }
        return;
    }
    const int pair = bid;
    const int d4 = t & 63, rg = t >> 6;      // 8 row groups
    __shared__ float4 smc[8][64];
    __shared__ float4 sme[8][64];
    __shared__ float mc[DIM], me[DIM];
    __shared__ float sb[2][2][OUTD];

    const float4* c4 = (const float4*)(claim + (size_t)pair * LCL * DIM);
    const float4* e4 = (const float4*)(evidence + (size_t)pair * LEV * DIM);
    float4 ac = make_float4(0.f, 0.f, 0.f, 0.f);
    float4 ae = make_float4(0.f, 0.f, 0.f, 0.f);
#pragma unroll 4
    for (int r = rg; r < LCL; r += 8) {
        const float4 v = c4[r * 64 + d4];
        ac.x += v.x; ac.y += v.y; ac.z += v.z; ac.w += v.w;
    }
#pragma unroll 4
    for (int r = rg; r < LEV; r += 8) {
        const float4 v = e4[r * 64 + d4];
        ae.x += v.x; ae.y += v.y; ae.z += v.z; ae.w += v.w;
    }
    smc[rg][d4] = ac; sme[rg][d4] = ae;
    __syncthreads();
    if (t < 64) {
        float4 s = make_float4(0.f, 0.f, 0.f, 0.f);
#pragma unroll
        for (int j = 0; j < 8; ++j) {
            const float4 v = smc[j][t];
            s.x += v.x; s.y += v.y; s.z += v.z; s.w += v.w;
        }
        ((float4*)mc)[t] = make_float4(s.x * (1.f / LCL), s.y * (1.f / LCL),
                                       s.z * (1.f / LCL), s.w * (1.f / LCL));
    } else if (t < 128) {
        const int u = t - 64;
        float4 s = make_float4(0.f, 0.f, 0.f, 0.f);
#pragma unroll
        for (int j = 0; j < 8; ++j) {
            const float4 v = sme[j][u];
            s.x += v.x; s.y += v.y; s.z += v.z; s.w += v.w;
        }
        ((float4*)me)[u] = make_float4(s.x * (1.f / LEV), s.y * (1.f / LEV),
                                       s.z * (1.f / LEV), s.w * (1.f / LEV));
    }
    __syncthreads();
    // side 0: claim-mean @ W1[D:] -> bias_e ; side 1: evid-mean @ W2[D:] -> bias_c
    const int side = t >> 8, o = t & 127, dh = (t >> 7) & 1;
    const float* W = side ? W2 : W1;
    const float* m = side ? me : mc;
    float s = 0.f;
#pragma unroll 8
    for (int i = 0; i < 128; ++i) {
        const int d = dh * 128 + i;
        s += m[d] * W[(size_t)(DIM + d) * OUTD + o];
    }
    sb[side][dh][o] = s;
    __syncthreads();
    if (t < 256) {
        const int sd = t >> 7, oo = t & 127;
        const float bv = sb[sd][0][oo] + sb[sd][1][oo];
        (sd ? bias_c : bias_e)[pair * OUTD + oo] = bv;
    }
}

// ---------------------------------------------------------------------------
// K2: fused scores + online-softmax + weighted sum. One block per (pair,side),
// interleaved by parity: even bid = evidence (L=512), odd = claim (L=256).
// 64-row fp32 LDS tile (66.6 KB -> 2 blocks/CU). Per tile:
//   [issue next-tile float4 loads -> regs]  (T14 async split)
//   MFMA scores: A-frags cvt'd fp32->bf16 in regs, B-frags from global WT
//   tanh-dot epilogue -> sred ; wave0 online softmax (running m,l)
//   weighted sum from LDS fp32 at float4 width  (no global re-read)
//   barrier ; ds_write next tile ; barrier
// ---------------------------------------------------------------------------
__global__ __launch_bounds__(512, 4) void k_fused(
    const float* __restrict__ claim, const float* __restrict__ evidence,
    const unsigned short* __restrict__ WT1, const unsigned short* __restrict__ WT2,
    const float* __restrict__ w2v, const float* __restrict__ w1v,
    const float* __restrict__ bias_e, const float* __restrict__ bias_c,
    const int* __restrict__ emask, const int* __restrict__ cmask,
    float* __restrict__ out)
{
    constexpr int SR4 = 65;                 // row stride in float4 (260 floats)
    __shared__ float4 sA4[64 * SR4];        // 66560 B fp32 tile
    __shared__ float sred[64][2];
    __shared__ float patt[64];
    __shared__ float stats[2];

    const int bid = blockIdx.x;
    const bool is_ev = (bid & 1) == 0;
    const int pair = bid >> 1;
    const float* __restrict__ seq  = is_ev ? evidence : claim;
    const unsigned short* __restrict__ WT = is_ev ? WT1 : WT2;
    const float* __restrict__ wvec = is_ev ? w2v : w1v;
    const float* __restrict__ bias = is_ev ? bias_e : bias_c;
    const int*   __restrict__ mask = is_ev ? emask : cmask;
    float* __restrict__ outp       = is_ev ? out + (size_t)BE * DIM : out;
    const int L  = is_ev ? LEV : LCL;
    const int NT = L >> 6;                  // 64-row tiles: 8 (ev) / 4 (claim)

    const int t = threadIdx.x;
    const int lane = t & 63;
    const int wv = t >> 6;                  // 0..7
    const int wrow = wv >> 1;               // 0..3 -> 16-row slice
    const int wcolg = wv & 1;               // 0..1 -> 64-col half
    const int q = lane >> 4, c16 = lane & 15;
    const int d4 = t & 63, rg = t >> 6;     // wsum mapping: 8 rows per rg

    float bc[4], wc[4];
#pragma unroll
    for (int ct = 0; ct < 4; ++ct) {
        const int col = wcolg * 64 + ct * 16 + c16;
        bc[ct] = bias[pair * OUTD + col];
        wc[ct] = wvec[col];
    }
    const unsigned short* wbase = WT + (size_t)(wcolg * 64 + c16) * DIM + q * 8;
    const float4* sp4 = (const float4*)(seq + (size_t)pair * L * DIM);

    // ---- prologue: stage tile 0 ----
    float4 nx[8];
#pragma unroll
    for (int j = 0; j < 8; ++j) nx[j] = sp4[t + j * 512];
#pragma unroll
    for (int j = 0; j < 8; ++j) {
        const int idx = t + j * 512;
        sA4[(idx >> 6) * SR4 + (idx & 63)] = nx[j];
    }
    __syncthreads();

    float4 Oac = make_float4(0.f, 0.f, 0.f, 0.f);
    float m_run = -INFINITY, l_run = 0.f;

    for (int tile = 0; tile < NT; ++tile) {
        const bool has_nxt = (tile + 1 < NT);
        // ---- T14: issue next-tile global loads now; write to LDS later ----
        if (has_nxt) {
            const float4* np4 = sp4 + (size_t)(tile + 1) * 4096;
#pragma unroll
            for (int j = 0; j < 8; ++j) nx[j] = np4[t + j * 512];
        }

        // ---- MFMA scores: wave covers rows wrow*16..+16, cols wcolg*64..+64 ----
        floatx4 acc[4];
#pragma unroll
        for (int ct = 0; ct < 4; ++ct) acc[ct] = (floatx4){0.f, 0.f, 0.f, 0.f};
        const int arow = wrow * 16 + c16;
#pragma unroll
        for (int ks = 0; ks < 8; ++ks) {
            bf16x8 bfr[4];
#pragma unroll
            for (int ct = 0; ct < 4; ++ct)
                bfr[ct] = *(const bf16x8*)(wbase + (size_t)ct * 16 * DIM + ks * 32);
            const float4 lo = sA4[arow * SR4 + ks * 8 + q * 2];
            const float4 hi = sA4[arow * SR4 + ks * 8 + q * 2 + 1];
            union { bf16x8 v; BF2 p[4]; } ua;
            ua.p[0].h = __float22bfloat162_rn(make_float2(lo.x, lo.y));
            ua.p[1].h = __float22bfloat162_rn(make_float2(lo.z, lo.w));
            ua.p[2].h = __float22bfloat162_rn(make_float2(hi.x, hi.y));
            ua.p[3].h = __float22bfloat162_rn(make_float2(hi.z, hi.w));
#pragma unroll
            for (int ct = 0; ct < 4; ++ct)
                acc[ct] = __builtin_amdgcn_mfma_f32_16x16x32_bf16(ua.v, bfr[ct], acc[ct], 0, 0, 0);
        }

        // ---- tanh-dot epilogue -> per-row score halves ----
#pragma unroll
        for (int reg = 0; reg < 4; ++reg) {
            float s = 0.f;
#pragma unroll
            for (int ct = 0; ct < 4; ++ct)
                s += fast_tanh(acc[ct][reg] + bc[ct]) * wc[ct];
#pragma unroll
            for (int off = 1; off < 16; off <<= 1) s += __shfl_xor(s, off, 64);
            if (c16 == 0)
                sred[wrow * 16 + q * 4 + reg][wcolg] = s;
        }
        __syncthreads();

        // ---- online softmax (wave 0 only; m_run/l_run replicated) ----
        if (t < 64) {
            float a = sred[t][0] + sred[t][1];
            a = mask[pair * L + tile * 64 + t] ? a : NEGV;
            float mx = a;
#pragma unroll
            for (int off = 1; off < 64; off <<= 1) mx = fmaxf(mx, __shfl_xor(mx, off, 64));
            const float newm = fmaxf(m_run, mx);
            const float e = expf(a - newm);
            patt[t] = e;
            float sm = e;
#pragma unroll
            for (int off = 1; off < 64; off <<= 1) sm += __shfl_xor(sm, off, 64);
            if (t == 0) { stats[0] = newm; stats[1] = sm; }
        }
        __syncthreads();
        const float newm = stats[0], tsum = stats[1];
        const float scale = expf(m_run - newm);   // first tile: expf(-inf)=0
        l_run = l_run * scale + tsum;
        m_run = newm;
        Oac.x *= scale; Oac.y *= scale; Oac.z *= scale; Oac.w *= scale;

        // ---- weighted sum from LDS fp32, float4 width ----
#pragma unroll
        for (int r = 0; r < 8; ++r) {
            const float pl = patt[rg * 8 + r];
            const float4 v = sA4[(rg * 8 + r) * SR4 + d4];
            Oac.x += pl * v.x; Oac.y += pl * v.y; Oac.z += pl * v.z; Oac.w += pl * v.w;
        }

        // ---- late half of T14: land next tile in LDS ----
        if (has_nxt) {
            __syncthreads();                       // all wsum reads done
#pragma unroll
            for (int j = 0; j < 8; ++j) {
                const int idx = t + j * 512;
                sA4[(idx >> 6) * SR4 + (idx & 63)] = nx[j];
            }
            __syncthreads();
        }
    }

    // ---- cross-rg reduce (reuse sA4), normalize, store ----
    __syncthreads();
    sA4[t] = Oac;
    __syncthreads();
    if (t < 64) {
        float4 s = make_float4(0.f, 0.f, 0.f, 0.f);
#pragma unroll
        for (int j = 0; j < 8; ++j) {
            const float4 v = sA4[j * 64 + t];
            s.x += v.x; s.y += v.y; s.z += v.z; s.w += v.w;
        }
        const float inv = 1.f / l_run;
        ((float4*)(outp + (size_t)pair * DIM))[t] =
            make_float4(s.x * inv, s.y * inv, s.z * inv, s.w * inv);
    }
}

// ---------------------------------------------------------------------------
extern "C" void kernel_launch(void* const* d_in, const int* in_sizes, int n_in,
                              void* d_out, int out_size, void* d_ws, size_t ws_size,
                              hipStream_t stream) {
    const float* claim    = (const float*)d_in[0];
    const int*   cmask    = (const int*)  d_in[1];
    const float* evidence = (const float*)d_in[2];
    const int*   emask    = (const int*)  d_in[3];
    const float* W1       = (const float*)d_in[4];
    const float* w2       = (const float*)d_in[5];
    const float* W2       = (const float*)d_in[6];
    const float* w1       = (const float*)d_in[7];
    float* out = (float*)d_out;

    float* ws = (float*)d_ws;
    float* bias_e = ws;                          // 256*128
    float* bias_c = bias_e + BE * OUTD;          // 256*128
    unsigned short* WT1 = (unsigned short*)(bias_c + BE * OUTD);
    unsigned short* WT2 = WT1 + OUTD * DIM;

    k_meanbias<<<BE + 2, 512, 0, stream>>>(claim, evidence, W1, W2,
                                           bias_e, bias_c, WT1, WT2);
    // output order: c_hat first (claim side), e_hat second (evidence side)
    k_fused<<<2 * BE, 512, 0, stream>>>(claim, evidence, WT1, WT2, w2, w1,
                                        bias_e, bias_c, emask, cmask, out);
}

// Round 3
// 399.013 us; speedup vs baseline: 1.2158x; 1.2158x over previous
//
#include <hip/hip_runtime.h>
#include <hip/hip_bf16.h>
#include <math.h>

#define BE   256
#define DIM  256
#define OUTD 128
#define LCL  256
#define LEV  512
#define NEGV -1e18f

typedef short  bf16x8  __attribute__((ext_vector_type(8)));
typedef float  floatx4 __attribute__((ext_vector_type(4)));

union BF1 { __hip_bfloat16 h; unsigned short u; };
union BF2 { __hip_bfloat162 h; unsigned int u; };

__device__ __forceinline__ float fast_tanh(float x) {
    float xc = fminf(fmaxf(x, -15.f), 15.f);
    float e = __expf(2.f * xc);                       // e^{2x}
    return (e - 1.f) * __builtin_amdgcn_rcpf(e + 1.f);
}

// ---------------------------------------------------------------------------
// K1: per-pair means (float4 streaming) + bias GEMVs + WT transpose fold.
// blocks [0,256): pair b -> means of claim (256 rows) and evidence (512 rows),
//   then bias_e = c_mean @ W1[D:], bias_c = e_mean @ W2[D:].
// blocks 256,257: convert+transpose W[:D] -> bf16 W^T (side = bid-256).
// ---------------------------------------------------------------------------
__global__ __launch_bounds__(512) void k_meanbias(
    const float* __restrict__ claim, const float* __restrict__ evidence,
    const float* __restrict__ W1, const float* __restrict__ W2,
    float* __restrict__ bias_e, float* __restrict__ bias_c,
    unsigned short* __restrict__ WT1, unsigned short* __restrict__ WT2)
{
    const int bid = blockIdx.x;
    const int t = threadIdx.x;
    if (bid >= BE) {
        const int side = bid - BE;
        const float* W = side ? W2 : W1;
        unsigned short* WT = side ? WT2 : WT1;
        for (int i = t; i < OUTD * DIM; i += 512) {
            const int d = i & (DIM - 1);
            const int n = i >> 8;
            BF1 c; c.h = __float2bfloat16(W[(size_t)d * OUTD + n]);
            WT[n * DIM + d] = c.u;           // contiguous writes per t-run
        }
        return;
    }
    const int pair = bid;
    const int d4 = t & 63, rg = t >> 6;      // 8 row groups
    __shared__ float4 smc[8][64];
    __shared__ float4 sme[8][64];
    __shared__ float mc[DIM], me[DIM];
    __shared__ float sb[2][2][OUTD];

    const float4* c4 = (const float4*)(claim + (size_t)pair * LCL * DIM);
    const float4* e4 = (const float4*)(evidence + (size_t)pair * LEV * DIM);
    float4 ac = make_float4(0.f, 0.f, 0.f, 0.f);
    float4 ae = make_float4(0.f, 0.f, 0.f, 0.f);
#pragma unroll 4
    for (int r = rg; r < LCL; r += 8) {
        const float4 v = c4[r * 64 + d4];
        ac.x += v.x; ac.y += v.y; ac.z += v.z; ac.w += v.w;
    }
#pragma unroll 4
    for (int r = rg; r < LEV; r += 8) {
        const float4 v = e4[r * 64 + d4];
        ae.x += v.x; ae.y += v.y; ae.z += v.z; ae.w += v.w;
    }
    smc[rg][d4] = ac; sme[rg][d4] = ae;
    __syncthreads();
    if (t < 64) {
        float4 s = make_float4(0.f, 0.f, 0.f, 0.f);
#pragma unroll
        for (int j = 0; j < 8; ++j) {
            const float4 v = smc[j][t];
            s.x += v.x; s.y += v.y; s.z += v.z; s.w += v.w;
        }
        ((float4*)mc)[t] = make_float4(s.x * (1.f / LCL), s.y * (1.f / LCL),
                                       s.z * (1.f / LCL), s.w * (1.f / LCL));
    } else if (t < 128) {
        const int u = t - 64;
        float4 s = make_float4(0.f, 0.f, 0.f, 0.f);
#pragma unroll
        for (int j = 0; j < 8; ++j) {
            const float4 v = sme[j][u];
            s.x += v.x; s.y += v.y; s.z += v.z; s.w += v.w;
        }
        ((float4*)me)[u] = make_float4(s.x * (1.f / LEV), s.y * (1.f / LEV),
                                       s.z * (1.f / LEV), s.w * (1.f / LEV));
    }
    __syncthreads();
    // side 0: claim-mean @ W1[D:] -> bias_e ; side 1: evid-mean @ W2[D:] -> bias_c
    const int side = t >> 8, o = t & 127, dh = (t >> 7) & 1;
    const float* W = side ? W2 : W1;
    const float* m = side ? me : mc;
    float s = 0.f;
#pragma unroll 8
    for (int i = 0; i < 128; ++i) {
        const int d = dh * 128 + i;
        s += m[d] * W[(size_t)(DIM + d) * OUTD + o];
    }
    sb[side][dh][o] = s;
    __syncthreads();
    if (t < 256) {
        const int sd = t >> 7, oo = t & 127;
        const float bv = sb[sd][0][oo] + sb[sd][1][oo];
        (sd ? bias_c : bias_e)[pair * OUTD + oo] = bv;
    }
}

// ---------------------------------------------------------------------------
// K2: fused scores + online-softmax + weighted sum. One block per (pair,side),
// interleaved by parity: even bid = evidence (L=512), odd = claim (L=256).
// 64-row fp32 LDS tile (66.6 KB -> 2 blocks/CU, LDS-limited). Per tile:
//   [issue next-tile float4 loads -> regs]  (T14 async split)
//   MFMA scores: A-frags cvt'd fp32->bf16 in regs, B-frags from global WT
//   tanh-dot epilogue -> sred ; wave0 online softmax (running m,l)
//   weighted sum from LDS fp32 at float4 width  (no global re-read)
//   barrier ; ds_write next tile ; barrier
// NOTE launch_bounds (512, 2): hipcc treats arg2 as min-BLOCKS/CU (CUDA
// semantics). (512,4) capped VGPRs at 64 -> nx[]/acc spilled to scratch ->
// 289 MB of HBM write traffic and 240 us. 2 blocks/CU = 128-VGPR budget,
// matches the LDS-limited occupancy anyway.
// ---------------------------------------------------------------------------
__global__ __launch_bounds__(512, 2) void k_fused(
    const float* __restrict__ claim, const float* __restrict__ evidence,
    const unsigned short* __restrict__ WT1, const unsigned short* __restrict__ WT2,
    const float* __restrict__ w2v, const float* __restrict__ w1v,
    const float* __restrict__ bias_e, const float* __restrict__ bias_c,
    const int* __restrict__ emask, const int* __restrict__ cmask,
    float* __restrict__ out)
{
    constexpr int SR4 = 65;                 // row stride in float4 (260 floats)
    __shared__ float4 sA4[64 * SR4];        // 66560 B fp32 tile
    __shared__ float sred[64][2];
    __shared__ float patt[64];
    __shared__ float stats[2];

    const int bid = blockIdx.x;
    const bool is_ev = (bid & 1) == 0;
    const int pair = bid >> 1;
    const float* __restrict__ seq  = is_ev ? evidence : claim;
    const unsigned short* __restrict__ WT = is_ev ? WT1 : WT2;
    const float* __restrict__ wvec = is_ev ? w2v : w1v;
    const float* __restrict__ bias = is_ev ? bias_e : bias_c;
    const int*   __restrict__ mask = is_ev ? emask : cmask;
    float* __restrict__ outp       = is_ev ? out + (size_t)BE * DIM : out;
    const int L  = is_ev ? LEV : LCL;
    const int NT = L >> 6;                  // 64-row tiles: 8 (ev) / 4 (claim)

    const int t = threadIdx.x;
    const int lane = t & 63;
    const int wv = t >> 6;                  // 0..7
    const int wrow = wv >> 1;               // 0..3 -> 16-row slice
    const int wcolg = wv & 1;               // 0..1 -> 64-col half
    const int q = lane >> 4, c16 = lane & 15;
    const int d4 = t & 63, rg = t >> 6;     // wsum mapping: 8 rows per rg

    float bc[4], wc[4];
#pragma unroll
    for (int ct = 0; ct < 4; ++ct) {
        const int col = wcolg * 64 + ct * 16 + c16;
        bc[ct] = bias[pair * OUTD + col];
        wc[ct] = wvec[col];
    }
    const unsigned short* wbase = WT + (size_t)(wcolg * 64 + c16) * DIM + q * 8;
    const float4* sp4 = (const float4*)(seq + (size_t)pair * L * DIM);

    // ---- prologue: stage tile 0 ----
    float4 nx[8];
#pragma unroll
    for (int j = 0; j < 8; ++j) nx[j] = sp4[t + j * 512];
#pragma unroll
    for (int j = 0; j < 8; ++j) {
        const int idx = t + j * 512;
        sA4[(idx >> 6) * SR4 + (idx & 63)] = nx[j];
    }
    __syncthreads();

    float4 Oac = make_float4(0.f, 0.f, 0.f, 0.f);
    float m_run = -INFINITY, l_run = 0.f;

    for (int tile = 0; tile < NT; ++tile) {
        const bool has_nxt = (tile + 1 < NT);
        // ---- T14: issue next-tile global loads now; write to LDS later ----
        if (has_nxt) {
            const float4* np4 = sp4 + (size_t)(tile + 1) * 4096;
#pragma unroll
            for (int j = 0; j < 8; ++j) nx[j] = np4[t + j * 512];
        }

        // ---- MFMA scores: wave covers rows wrow*16..+16, cols wcolg*64..+64 ----
        floatx4 acc[4];
#pragma unroll
        for (int ct = 0; ct < 4; ++ct) acc[ct] = (floatx4){0.f, 0.f, 0.f, 0.f};
        const int arow = wrow * 16 + c16;
#pragma unroll
        for (int ks = 0; ks < 8; ++ks) {
            bf16x8 bfr[4];
#pragma unroll
            for (int ct = 0; ct < 4; ++ct)
                bfr[ct] = *(const bf16x8*)(wbase + (size_t)ct * 16 * DIM + ks * 32);
            const float4 lo = sA4[arow * SR4 + ks * 8 + q * 2];
            const float4 hi = sA4[arow * SR4 + ks * 8 + q * 2 + 1];
            union { bf16x8 v; BF2 p[4]; } ua;
            ua.p[0].h = __float22bfloat162_rn(make_float2(lo.x, lo.y));
            ua.p[1].h = __float22bfloat162_rn(make_float2(lo.z, lo.w));
            ua.p[2].h = __float22bfloat162_rn(make_float2(hi.x, hi.y));
            ua.p[3].h = __float22bfloat162_rn(make_float2(hi.z, hi.w));
#pragma unroll
            for (int ct = 0; ct < 4; ++ct)
                acc[ct] = __builtin_amdgcn_mfma_f32_16x16x32_bf16(ua.v, bfr[ct], acc[ct], 0, 0, 0);
        }

        // ---- tanh-dot epilogue -> per-row score halves ----
#pragma unroll
        for (int reg = 0; reg < 4; ++reg) {
            float s = 0.f;
#pragma unroll
            for (int ct = 0; ct < 4; ++ct)
                s += fast_tanh(acc[ct][reg] + bc[ct]) * wc[ct];
#pragma unroll
            for (int off = 1; off < 16; off <<= 1) s += __shfl_xor(s, off, 64);
            if (c16 == 0)
                sred[wrow * 16 + q * 4 + reg][wcolg] = s;
        }
        __syncthreads();

        // ---- online softmax (wave 0 only; m_run/l_run replicated) ----
        if (t < 64) {
            float a = sred[t][0] + sred[t][1];
            a = mask[pair * L + tile * 64 + t] ? a : NEGV;
            float mx = a;
#pragma unroll
            for (int off = 1; off < 64; off <<= 1) mx = fmaxf(mx, __shfl_xor(mx, off, 64));
            const float newm = fmaxf(m_run, mx);
            const float e = expf(a - newm);
            patt[t] = e;
            float sm = e;
#pragma unroll
            for (int off = 1; off < 64; off <<= 1) sm += __shfl_xor(sm, off, 64);
            if (t == 0) { stats[0] = newm; stats[1] = sm; }
        }
        __syncthreads();
        const float newm = stats[0], tsum = stats[1];
        const float scale = expf(m_run - newm);   // first tile: expf(-inf)=0
        l_run = l_run * scale + tsum;
        m_run = newm;
        Oac.x *= scale; Oac.y *= scale; Oac.z *= scale; Oac.w *= scale;

        // ---- weighted sum from LDS fp32, float4 width ----
#pragma unroll
        for (int r = 0; r < 8; ++r) {
            const float pl = patt[rg * 8 + r];
            const float4 v = sA4[(rg * 8 + r) * SR4 + d4];
            Oac.x += pl * v.x; Oac.y += pl * v.y; Oac.z += pl * v.z; Oac.w += pl * v.w;
        }

        // ---- late half of T14: land next tile in LDS ----
        if (has_nxt) {
            __syncthreads();                       // all wsum reads done
#pragma unroll
            for (int j = 0; j < 8; ++j) {
                const int idx = t + j * 512;
                sA4[(idx >> 6) * SR4 + (idx & 63)] = nx[j];
            }
            __syncthreads();
        }
    }

    // ---- cross-rg reduce (reuse sA4), normalize, store ----
    __syncthreads();
    sA4[t] = Oac;
    __syncthreads();
    if (t < 64) {
        float4 s = make_float4(0.f, 0.f, 0.f, 0.f);
#pragma unroll
        for (int j = 0; j < 8; ++j) {
            const float4 v = sA4[j * 64 + t];
            s.x += v.x; s.y += v.y; s.z += v.z; s.w += v.w;
        }
        const float inv = 1.f / l_run;
        ((float4*)(outp + (size_t)pair * DIM))[t] =
            make_float4(s.x * inv, s.y * inv, s.z * inv, s.w * inv);
    }
}

// ---------------------------------------------------------------------------
extern "C" void kernel_launch(void* const* d_in, const int* in_sizes, int n_in,
                              void* d_out, int out_size, void* d_ws, size_t ws_size,
                              hipStream_t stream) {
    const float* claim    = (const float*)d_in[0];
    const int*   cmask    = (const int*)  d_in[1];
    const float* evidence = (const float*)d_in[2];
    const int*   emask    = (const int*)  d_in[3];
    const float* W1       = (const float*)d_in[4];
    const float* w2       = (const float*)d_in[5];
    const float* W2       = (const float*)d_in[6];
    const float* w1       = (const float*)d_in[7];
    float* out = (float*)d_out;

    float* ws = (float*)d_ws;
    float* bias_e = ws;                          // 256*128
    float* bias_c = bias_e + BE * OUTD;          // 256*128
    unsigned short* WT1 = (unsigned short*)(bias_c + BE * OUTD);
    unsigned short* WT2 = WT1 + OUTD * DIM;

    k_meanbias<<<BE + 2, 512, 0, stream>>>(claim, evidence, W1, W2,
                                           bias_e, bias_c, WT1, WT2);
    // output order: c_hat first (claim side), e_hat second (evidence side)
    k_fused<<<2 * BE, 512, 0, stream>>>(claim, evidence, WT1, WT2, w2, w1,
                                        bias_e, bias_c, emask, cmask, out);
}

// Round 4
// 349.618 us; speedup vs baseline: 1.3876x; 1.1413x over previous
//
#include <hip/hip_runtime.h>
#include <hip/hip_bf16.h>
#include <math.h>

#define BE   256
#define DIM  256
#define OUTD 128
#define LCL  256
#define LEV  512
#define NEGV -1e18f

typedef short  bf16x8  __attribute__((ext_vector_type(8)));
typedef float  floatx4 __attribute__((ext_vector_type(4)));

union BF1 { __hip_bfloat16 h; unsigned short u; };
union BF2 { __hip_bfloat162 h; unsigned int u; };

__device__ __forceinline__ float fast_tanh(float x) {
    float xc = fminf(fmaxf(x, -15.f), 15.f);
    float e = __expf(2.f * xc);                       // e^{2x}
    return (e - 1.f) * __builtin_amdgcn_rcpf(e + 1.f);
}

// Direct global->LDS DMA, 16B per lane. Dest must be wave-uniform base
// (HW writes lane i at base + i*16); source is per-lane. (Rule: LDS row
// must be linear; our +pad lives BETWEEN rows, so each 1KB row is legal.)
__device__ __forceinline__ void gl_lds16(const float4* g, float4* l) {
    __builtin_amdgcn_global_load_lds(
        (const __attribute__((address_space(1))) unsigned int*)(const void*)g,
        (__attribute__((address_space(3))) unsigned int*)(void*)l,
        16, 0, 0);
}

// ---------------------------------------------------------------------------
// K1: per-pair means (float4 streaming, unroll 8 for ILP) + bias GEMVs +
// WT transpose fold. blocks [0,256): pair b. blocks 256,257: W[:D] -> bf16 W^T.
// ---------------------------------------------------------------------------
__global__ __launch_bounds__(512) void k_meanbias(
    const float* __restrict__ claim, const float* __restrict__ evidence,
    const float* __restrict__ W1, const float* __restrict__ W2,
    float* __restrict__ bias_e, float* __restrict__ bias_c,
    unsigned short* __restrict__ WT1, unsigned short* __restrict__ WT2)
{
    const int bid = blockIdx.x;
    const int t = threadIdx.x;
    if (bid >= BE) {
        const int side = bid - BE;
        const float* W = side ? W2 : W1;
        unsigned short* WT = side ? WT2 : WT1;
        for (int i = t; i < OUTD * DIM; i += 512) {
            const int d = i & (DIM - 1);
            const int n = i >> 8;
            BF1 c; c.h = __float2bfloat16(W[(size_t)d * OUTD + n]);
            WT[n * DIM + d] = c.u;           // contiguous writes per t-run
        }
        return;
    }
    const int pair = bid;
    const int d4 = t & 63, rg = t >> 6;      // 8 row groups
    __shared__ float4 smc[8][64];
    __shared__ float4 sme[8][64];
    __shared__ float mc[DIM], me[DIM];
    __shared__ float sb[2][2][OUTD];

    const float4* c4 = (const float4*)(claim + (size_t)pair * LCL * DIM);
    const float4* e4 = (const float4*)(evidence + (size_t)pair * LEV * DIM);
    float4 ac = make_float4(0.f, 0.f, 0.f, 0.f);
    float4 ae = make_float4(0.f, 0.f, 0.f, 0.f);
#pragma unroll 8
    for (int r = rg; r < LCL; r += 8) {
        const float4 v = c4[r * 64 + d4];
        ac.x += v.x; ac.y += v.y; ac.z += v.z; ac.w += v.w;
    }
#pragma unroll 8
    for (int r = rg; r < LEV; r += 8) {
        const float4 v = e4[r * 64 + d4];
        ae.x += v.x; ae.y += v.y; ae.z += v.z; ae.w += v.w;
    }
    smc[rg][d4] = ac; sme[rg][d4] = ae;
    __syncthreads();
    if (t < 64) {
        float4 s = make_float4(0.f, 0.f, 0.f, 0.f);
#pragma unroll
        for (int j = 0; j < 8; ++j) {
            const float4 v = smc[j][t];
            s.x += v.x; s.y += v.y; s.z += v.z; s.w += v.w;
        }
        ((float4*)mc)[t] = make_float4(s.x * (1.f / LCL), s.y * (1.f / LCL),
                                       s.z * (1.f / LCL), s.w * (1.f / LCL));
    } else if (t < 128) {
        const int u = t - 64;
        float4 s = make_float4(0.f, 0.f, 0.f, 0.f);
#pragma unroll
        for (int j = 0; j < 8; ++j) {
            const float4 v = sme[j][u];
            s.x += v.x; s.y += v.y; s.z += v.z; s.w += v.w;
        }
        ((float4*)me)[u] = make_float4(s.x * (1.f / LEV), s.y * (1.f / LEV),
                                       s.z * (1.f / LEV), s.w * (1.f / LEV));
    }
    __syncthreads();
    // side 0: claim-mean @ W1[D:] -> bias_e ; side 1: evid-mean @ W2[D:] -> bias_c
    const int side = t >> 8, o = t & 127, dh = (t >> 7) & 1;
    const float* W = side ? W2 : W1;
    const float* m = side ? me : mc;
    float s = 0.f;
#pragma unroll 8
    for (int i = 0; i < 128; ++i) {
        const int d = dh * 128 + i;
        s += m[d] * W[(size_t)(DIM + d) * OUTD + o];
    }
    sb[side][dh][o] = s;
    __syncthreads();
    if (t < 256) {
        const int sd = t >> 7, oo = t & 127;
        const float bv = sb[sd][0][oo] + sb[sd][1][oo];
        (sd ? bias_c : bias_e)[pair * OUTD + oo] = bv;
    }
}

// ---------------------------------------------------------------------------
// K2: fused scores + online-softmax + weighted sum. One block per (pair,side),
// parity-interleaved: even bid = evidence (L=512), odd = claim (L=256).
// DOUBLE-BUFFERED fp32 LDS tiles (2 x 66.5 KB = 133 KB -> 1 block/CU),
// staged via global_load_lds DMA (NO register intermediate -> no spill;
// R3's nx[8] register prefetch spilled: 195 MB scratch writes/launch).
// Per tile: [syncthreads drains prev DMA] -> issue next-tile DMA into other
// buffer -> MFMA scores (A cvt fp32->bf16 in regs, B from L2-resident WT) ->
// tanh-dot epilogue -> online softmax (wave0) -> fp32 wsum from LDS.
// ---------------------------------------------------------------------------
__global__ __launch_bounds__(512) void k_fused(
    const float* __restrict__ claim, const float* __restrict__ evidence,
    const unsigned short* __restrict__ WT1, const unsigned short* __restrict__ WT2,
    const float* __restrict__ w2v, const float* __restrict__ w1v,
    const float* __restrict__ bias_e, const float* __restrict__ bias_c,
    const int* __restrict__ emask, const int* __restrict__ cmask,
    float* __restrict__ out)
{
    constexpr int SR4 = 65;                 // row stride in float4 (pad between rows)
    __shared__ float4 sA4[2][64 * SR4];     // 2 x 66560 B
    __shared__ float sred[64][2];
    __shared__ float patt[64];
    __shared__ float stats[2];

    const int bid = blockIdx.x;
    const bool is_ev = (bid & 1) == 0;
    const int pair = bid >> 1;
    const float* __restrict__ seq  = is_ev ? evidence : claim;
    const unsigned short* __restrict__ WT = is_ev ? WT1 : WT2;
    const float* __restrict__ wvec = is_ev ? w2v : w1v;
    const float* __restrict__ bias = is_ev ? bias_e : bias_c;
    const int*   __restrict__ mask = is_ev ? emask : cmask;
    float* __restrict__ outp       = is_ev ? out + (size_t)BE * DIM : out;
    const int L  = is_ev ? LEV : LCL;
    const int NT = L >> 6;                  // 64-row tiles: 8 (ev) / 4 (claim)

    const int t = threadIdx.x;
    const int lane = t & 63;
    const int wv = t >> 6;                  // 0..7
    const int wrow = wv >> 1;               // 0..3 -> 16-row slice
    const int wcolg = wv & 1;               // 0..1 -> 64-col half
    const int q = lane >> 4, c16 = lane & 15;
    const int d4 = t & 63, rg = t >> 6;     // wsum mapping: 8 rows per rg

    float bc[4], wc[4];
#pragma unroll
    for (int ct = 0; ct < 4; ++ct) {
        const int col = wcolg * 64 + ct * 16 + c16;
        bc[ct] = bias[pair * OUTD + col];
        wc[ct] = wvec[col];
    }
    const unsigned short* wbase = WT + (size_t)(wcolg * 64 + c16) * DIM + q * 8;
    const float4* sp4 = (const float4*)(seq + (size_t)pair * L * DIM);

    // each wave DMAs 8 rows (1KB each: 64 lanes x 16B, linear dest)
    auto stage = [&](int buf, int tile) {
        const float4* base = sp4 + (size_t)tile * 4096;
#pragma unroll
        for (int j = 0; j < 8; ++j) {
            const int row = wv * 8 + j;
            gl_lds16(base + row * 64 + lane, &sA4[buf][row * SR4]);
        }
    };

    stage(0, 0);                            // prologue: tile 0 -> buf 0
    int cur = 0;

    float4 Oac = make_float4(0.f, 0.f, 0.f, 0.f);
    float m_run = -INFINITY, l_run = 0.f;

    for (int tile = 0; tile < NT; ++tile) {
        __syncthreads();                    // drains DMA: buf[cur] ready; prev wsum done
        if (tile + 1 < NT) stage(cur ^ 1, tile + 1);

        // ---- MFMA scores: wave covers rows wrow*16..+16, cols wcolg*64..+64 ----
        floatx4 acc[4];
#pragma unroll
        for (int ct = 0; ct < 4; ++ct) acc[ct] = (floatx4){0.f, 0.f, 0.f, 0.f};
        const int arow = wrow * 16 + c16;
#pragma unroll
        for (int ks = 0; ks < 8; ++ks) {
            bf16x8 bfr[4];
#pragma unroll
            for (int ct = 0; ct < 4; ++ct)
                bfr[ct] = *(const bf16x8*)(wbase + (size_t)ct * 16 * DIM + ks * 32);
            const float4 lo = sA4[cur][arow * SR4 + ks * 8 + q * 2];
            const float4 hi = sA4[cur][arow * SR4 + ks * 8 + q * 2 + 1];
            union { bf16x8 v; BF2 p[4]; } ua;
            ua.p[0].h = __float22bfloat162_rn(make_float2(lo.x, lo.y));
            ua.p[1].h = __float22bfloat162_rn(make_float2(lo.z, lo.w));
            ua.p[2].h = __float22bfloat162_rn(make_float2(hi.x, hi.y));
            ua.p[3].h = __float22bfloat162_rn(make_float2(hi.z, hi.w));
#pragma unroll
            for (int ct = 0; ct < 4; ++ct)
                acc[ct] = __builtin_amdgcn_mfma_f32_16x16x32_bf16(ua.v, bfr[ct], acc[ct], 0, 0, 0);
        }

        // ---- tanh-dot epilogue -> per-row score halves ----
#pragma unroll
        for (int reg = 0; reg < 4; ++reg) {
            float s = 0.f;
#pragma unroll
            for (int ct = 0; ct < 4; ++ct)
                s += fast_tanh(acc[ct][reg] + bc[ct]) * wc[ct];
#pragma unroll
            for (int off = 1; off < 16; off <<= 1) s += __shfl_xor(s, off, 64);
            if (c16 == 0)
                sred[wrow * 16 + q * 4 + reg][wcolg] = s;
        }
        __syncthreads();

        // ---- online softmax (wave 0 only; m_run/l_run replicated) ----
        if (t < 64) {
            float a = sred[t][0] + sred[t][1];
            a = mask[pair * L + tile * 64 + t] ? a : NEGV;
            float mx = a;
#pragma unroll
            for (int off = 1; off < 64; off <<= 1) mx = fmaxf(mx, __shfl_xor(mx, off, 64));
            const float newm = fmaxf(m_run, mx);
            const float e = expf(a - newm);
            patt[t] = e;
            float sm = e;
#pragma unroll
            for (int off = 1; off < 64; off <<= 1) sm += __shfl_xor(sm, off, 64);
            if (t == 0) { stats[0] = newm; stats[1] = sm; }
        }
        __syncthreads();
        const float newm = stats[0], tsum = stats[1];
        const float scale = expf(m_run - newm);   // first tile: expf(-inf)=0
        l_run = l_run * scale + tsum;
        m_run = newm;
        Oac.x *= scale; Oac.y *= scale; Oac.z *= scale; Oac.w *= scale;

        // ---- weighted sum from LDS fp32, float4 width (row-contiguous) ----
#pragma unroll
        for (int r = 0; r < 8; ++r) {
            const float pl = patt[rg * 8 + r];
            const float4 v = sA4[cur][(rg * 8 + r) * SR4 + d4];
            Oac.x += pl * v.x; Oac.y += pl * v.y; Oac.z += pl * v.z; Oac.w += pl * v.w;
        }
        cur ^= 1;
    }

    // ---- cross-rg reduce (reuse sA4), normalize, store ----
    __syncthreads();
    ((float4*)sA4)[t] = Oac;
    __syncthreads();
    if (t < 64) {
        float4 s = make_float4(0.f, 0.f, 0.f, 0.f);
#pragma unroll
        for (int j = 0; j < 8; ++j) {
            const float4 v = ((float4*)sA4)[j * 64 + t];
            s.x += v.x; s.y += v.y; s.z += v.z; s.w += v.w;
        }
        const float inv = 1.f / l_run;
        ((float4*)(outp + (size_t)pair * DIM))[t] =
            make_float4(s.x * inv, s.y * inv, s.z * inv, s.w * inv);
    }
}

// ---------------------------------------------------------------------------
extern "C" void kernel_launch(void* const* d_in, const int* in_sizes, int n_in,
                              void* d_out, int out_size, void* d_ws, size_t ws_size,
                              hipStream_t stream) {
    const float* claim    = (const float*)d_in[0];
    const int*   cmask    = (const int*)  d_in[1];
    const float* evidence = (const float*)d_in[2];
    const int*   emask    = (const int*)  d_in[3];
    const float* W1       = (const float*)d_in[4];
    const float* w2       = (const float*)d_in[5];
    const float* W2       = (const float*)d_in[6];
    const float* w1       = (const float*)d_in[7];
    float* out = (float*)d_out;

    float* ws = (float*)d_ws;
    float* bias_e = ws;                          // 256*128
    float* bias_c = bias_e + BE * OUTD;          // 256*128
    unsigned short* WT1 = (unsigned short*)(bias_c + BE * OUTD);
    unsigned short* WT2 = WT1 + OUTD * DIM;

    k_meanbias<<<BE + 2, 512, 0, stream>>>(claim, evidence, W1, W2,
                                           bias_e, bias_c, WT1, WT2);
    // output order: c_hat first (claim side), e_hat second (evidence side)
    k_fused<<<2 * BE, 512, 0, stream>>>(claim, evidence, WT1, WT2, w2, w1,
                                        bias_e, bias_c, emask, cmask, out);
}